// Round 1
// baseline (2295.001 us; speedup 1.0000x reference)
//
#include <hip/hip_runtime.h>
#include <math.h>

// Problem constants
#define BB 32
#define TT 512
#define INF_ 128
#define HH 256
#define H3 768
#define NHEADS 4
#define HDIM 64

typedef _Float16 half_t;
typedef half_t half2_t __attribute__((ext_vector_type(2)));
typedef half_t half4_t __attribute__((ext_vector_type(4)));
typedef half_t f16x8 __attribute__((ext_vector_type(8)));
typedef float f32x4 __attribute__((ext_vector_type(4)));

// ---------------- wave helpers (wave = 64 on CDNA) ----------------
__device__ __forceinline__ float wsum(float v) {
#pragma unroll
  for (int o = 32; o > 0; o >>= 1) v += __shfl_xor(v, o, 64);
  return v;
}
__device__ __forceinline__ float wmax(float v) {
#pragma unroll
  for (int o = 32; o > 0; o >>= 1) v = fmaxf(v, __shfl_xor(v, o, 64));
  return v;
}

// ---------------- fp32 -> f16 cast (n % 1024 == 0) ----------------
__global__ void castk(const float* __restrict__ s, half_t* __restrict__ d, int n) {
  int i = (blockIdx.x * 256 + threadIdx.x) * 4;
  if (i < n) {
    float4 v = *(const float4*)(s + i);
    half4_t o = {(half_t)v.x, (half_t)v.y, (half_t)v.z, (half_t)v.w};
    *(half4_t*)(d + i) = o;
  }
}

// ---------------- MFMA f16 GEMM: C[M,N] = A[M,K] * B[N,K]^T + bias -------
__global__ __launch_bounds__(256) void gemm_f16(
    const half_t* __restrict__ A, const half_t* __restrict__ B,
    const float* __restrict__ bias, float* __restrict__ C,
    int M, int N, int K) {
  __shared__ __align__(16) half_t As[128][40];
  __shared__ __align__(16) half_t Bs[64][40];
  const int tid = threadIdx.x;
  const int wave = tid >> 6, lane = tid & 63;
  const int m0 = blockIdx.y * 128, n0 = blockIdx.x * 64;
  const int mrow = lane & 15, quad = lane >> 4;
  f32x4 acc00 = {0.f, 0.f, 0.f, 0.f}, acc01 = acc00, acc02 = acc00, acc03 = acc00;
  f32x4 acc10 = acc00, acc11 = acc00, acc12 = acc00, acc13 = acc00;
  for (int k0 = 0; k0 < K; k0 += 32) {
    __syncthreads();  // previous iter's fragments consumed
#pragma unroll
    for (int u = 0; u < 2; ++u) {  // stage A: 128 rows x 32 halfs
      int idx = tid + u * 256;
      int row = idx >> 2, seg = idx & 3;
      *(f16x8*)&As[row][seg * 8] =
          *(const f16x8*)&A[(size_t)(m0 + row) * K + k0 + seg * 8];
    }
    {  // stage B: 64 rows x 32 halfs
      int row = tid >> 2, seg = tid & 3;
      *(f16x8*)&Bs[row][seg * 8] =
          *(const f16x8*)&B[(size_t)(n0 + row) * K + k0 + seg * 8];
    }
    __syncthreads();
    f16x8 af0 = *(const f16x8*)&As[wave * 32 + mrow][quad * 8];
    f16x8 af1 = *(const f16x8*)&As[wave * 32 + 16 + mrow][quad * 8];
    f16x8 bf0 = *(const f16x8*)&Bs[mrow][quad * 8];
    f16x8 bf1 = *(const f16x8*)&Bs[16 + mrow][quad * 8];
    f16x8 bf2 = *(const f16x8*)&Bs[32 + mrow][quad * 8];
    f16x8 bf3 = *(const f16x8*)&Bs[48 + mrow][quad * 8];
    acc00 = __builtin_amdgcn_mfma_f32_16x16x32_f16(af0, bf0, acc00, 0, 0, 0);
    acc01 = __builtin_amdgcn_mfma_f32_16x16x32_f16(af0, bf1, acc01, 0, 0, 0);
    acc02 = __builtin_amdgcn_mfma_f32_16x16x32_f16(af0, bf2, acc02, 0, 0, 0);
    acc03 = __builtin_amdgcn_mfma_f32_16x16x32_f16(af0, bf3, acc03, 0, 0, 0);
    acc10 = __builtin_amdgcn_mfma_f32_16x16x32_f16(af1, bf0, acc10, 0, 0, 0);
    acc11 = __builtin_amdgcn_mfma_f32_16x16x32_f16(af1, bf1, acc11, 0, 0, 0);
    acc12 = __builtin_amdgcn_mfma_f32_16x16x32_f16(af1, bf2, acc12, 0, 0, 0);
    acc13 = __builtin_amdgcn_mfma_f32_16x16x32_f16(af1, bf3, acc13, 0, 0, 0);
  }
  float bv0 = bias ? bias[n0 + mrow] : 0.f;
  float bv1 = bias ? bias[n0 + 16 + mrow] : 0.f;
  float bv2 = bias ? bias[n0 + 32 + mrow] : 0.f;
  float bv3 = bias ? bias[n0 + 48 + mrow] : 0.f;
  const int rb = m0 + wave * 32 + quad * 4;
#pragma unroll
  for (int r = 0; r < 4; ++r) {
    float* c0 = C + (size_t)(rb + r) * N + n0;
    c0[mrow] = acc00[r] + bv0;
    c0[16 + mrow] = acc01[r] + bv1;
    c0[32 + mrow] = acc02[r] + bv2;
    c0[48 + mrow] = acc03[r] + bv3;
    float* c1 = C + (size_t)(rb + 16 + r) * N + n0;
    c1[mrow] = acc10[r] + bv0;
    c1[16 + mrow] = acc11[r] + bv1;
    c1[32 + mrow] = acc12[r] + bv2;
    c1[48 + mrow] = acc13[r] + bv3;
  }
}

// ---------------- GRU recurrence: MFMA GEMV (weights resident in VGPRs) ---
// Per block: 1 batch, 12 waves. Per step, g[768] = W_hh[768,256] @ h[256] is
// computed on the matrix pipe: A-operand = h broadcast across all 16 M-rows
// (A-frag layout: lane l holds h[(l>>4)*8+i], independent of l&15, so the
// LDS read is a 4-address broadcast ds_read_b128). All 16 D rows are then
// identical copies of g, so acc[0] of lanes 0-15 is the result. B-operand =
// W rows as f16 fragments held PERMANENTLY in registers (32 frags = 128
// VGPR/thread; wave w owns gate rows [64w, 64w+64)). 384 MFMA/step replace
// ~98k FDOT2 lane-ops; removes the 152 KB/step LDS weight stream that made
// the previous (R14 FDOT2) version jointly VALU- and LDS-bound at 693 us.
// Gate combine: g exchanged through a 3 KB LDS buffer, 256 lanes apply the
// sigmoid/tanh recurrence (h_prev in registers), write h back as f16.
__device__ __forceinline__ f16x8 ldw8(const float* p) {
  float4 a = *(const float4*)p;
  float4 b = *(const float4*)(p + 4);
  return f16x8{(half_t)a.x, (half_t)a.y, (half_t)a.z, (half_t)a.w,
               (half_t)b.x, (half_t)b.y, (half_t)b.z, (half_t)b.w};
}

#define WDECL(nt) f16x8 w##nt##_0, w##nt##_1, w##nt##_2, w##nt##_3, \
                        w##nt##_4, w##nt##_5, w##nt##_6, w##nt##_7;
#define WLOAD(nt)                                                          \
  {                                                                        \
    const float* wr = Whh + (size_t)(64 * w + 16 * nt + col) * HH + quad * 8; \
    w##nt##_0 = ldw8(wr + 0 * 32);                                         \
    w##nt##_1 = ldw8(wr + 1 * 32);                                         \
    w##nt##_2 = ldw8(wr + 2 * 32);                                         \
    w##nt##_3 = ldw8(wr + 3 * 32);                                         \
    w##nt##_4 = ldw8(wr + 4 * 32);                                         \
    w##nt##_5 = ldw8(wr + 5 * 32);                                         \
    w##nt##_6 = ldw8(wr + 6 * 32);                                         \
    w##nt##_7 = ldw8(wr + 7 * 32);                                         \
  }
// one K-tile: 4 MFMAs (one per owned N-tile), consecutive MFMAs hit
// different accumulators -> dep chains spaced by 4 on the matrix pipe
#define MSTEP(ak, kt)                                                        \
  acc0 = __builtin_amdgcn_mfma_f32_16x16x32_f16(ak, w0_##kt, acc0, 0, 0, 0); \
  acc1 = __builtin_amdgcn_mfma_f32_16x16x32_f16(ak, w1_##kt, acc1, 0, 0, 0); \
  acc2 = __builtin_amdgcn_mfma_f32_16x16x32_f16(ak, w2_##kt, acc2, 0, 0, 0); \
  acc3 = __builtin_amdgcn_mfma_f32_16x16x32_f16(ak, w3_##kt, acc3, 0, 0, 0);

__global__ __launch_bounds__(768) void gru_layer(
    const float* __restrict__ xp, const float* __restrict__ Whh,
    const float* __restrict__ bhh, float* __restrict__ out,
    half_t* __restrict__ out16) {
  __shared__ __align__(16) half_t hs[2][256];   // packed f16 hidden state
  __shared__ __align__(16) float gbuf[768];     // g = W_hh @ h exchange
  const int tid = threadIdx.x;
  const int w = tid >> 6, lane = tid & 63;
  const int col = lane & 15, quad = lane >> 4;
  const int b = blockIdx.x;
  const bool wf32 = (out != nullptr);  // uniform: layer 0 skips fp32 h-store

  // B-fragments: wave w owns gate rows [64w, 64w+64) as 4 N-tiles x 8 K-tiles.
  // Waves 0-3 -> r rows [0,256), 4-7 -> z, 8-11 -> n.
  WDECL(0) WDECL(1) WDECL(2) WDECL(3)
  WLOAD(0) WLOAD(1) WLOAD(2) WLOAD(3)

  float br = 0.f, bz = 0.f, bn = 0.f, hprev = 0.f;
  if (tid < 256) {
    br = bhh[tid];
    bz = bhh[HH + tid];
    bn = bhh[2 * HH + tid];
    hs[0][tid] = (half_t)0.f;
  }
  __syncthreads();

  const float* xrow = xp + (size_t)b * TT * H3;
  half_t* orow16 = out16 + (size_t)b * TT * HH;
  float* orow = wf32 ? out + (size_t)b * TT * HH : nullptr;

  for (int t = 0; t < TT; ++t) {
    // prefetch this step's x-projection early (consumed after the barrier)
    float xr = 0.f, xz = 0.f, xn = 0.f;
    if (tid < 256) {
      xr = xrow[tid];
      xz = xrow[HH + tid];
      xn = xrow[2 * HH + tid];
    }
    // A-fragments: 8 broadcast b128 reads of h (16B at quad*16 + kt*64)
    const half_t* hb = &hs[t & 1][quad * 8];
    f16x8 a0 = *(const f16x8*)(hb + 0 * 32);
    f16x8 a1 = *(const f16x8*)(hb + 1 * 32);
    f16x8 a2 = *(const f16x8*)(hb + 2 * 32);
    f16x8 a3 = *(const f16x8*)(hb + 3 * 32);
    f16x8 a4 = *(const f16x8*)(hb + 4 * 32);
    f16x8 a5 = *(const f16x8*)(hb + 5 * 32);
    f16x8 a6 = *(const f16x8*)(hb + 6 * 32);
    f16x8 a7 = *(const f16x8*)(hb + 7 * 32);
    f32x4 acc0 = {0.f, 0.f, 0.f, 0.f}, acc1 = acc0, acc2 = acc0, acc3 = acc0;
    MSTEP(a0, 0) MSTEP(a1, 1) MSTEP(a2, 2) MSTEP(a3, 3)
    MSTEP(a4, 4) MSTEP(a5, 5) MSTEP(a6, 6) MSTEP(a7, 7)
    if (lane < 16) {  // quad==0: D row 0; all rows identical (A broadcast)
      gbuf[64 * w + lane] = acc0[0];
      gbuf[64 * w + 16 + lane] = acc1[0];
      gbuf[64 * w + 32 + lane] = acc2[0];
      gbuf[64 * w + 48 + lane] = acc3[0];
    }
    __syncthreads();  // g complete
    if (tid < 256) {
      float ar = gbuf[tid], az = gbuf[HH + tid], an = gbuf[2 * HH + tid];
      float rg = 1.f / (1.f + __expf(-(xr + ar + br)));
      float zg = 1.f / (1.f + __expf(-(xz + az + bz)));
      float ng = 2.f / (1.f + __expf(-2.f * (xn + rg * (an + bn)))) - 1.f;  // tanh, inf-safe
      float hnew = (1.f - zg) * ng + zg * hprev;
      hprev = hnew;
      hs[(t + 1) & 1][tid] = (half_t)hnew;
      orow16[tid] = (half_t)hnew;
      if (wf32) orow[tid] = hnew;
    }
    __syncthreads();  // h(t+1) visible before next step's A-frag reads
    xrow += H3;
    orow16 += HH;
    if (wf32) orow += HH;
  }
}

// ---------------- gat_W transpose -> f16: [4,256,64] -> [256 cols][256 k] --
__global__ void gat_wt(const float* __restrict__ W, half_t* __restrict__ Wt) {
  int idx = blockIdx.x * 256 + threadIdx.x;  // [0, 65536)
  int col = idx >> 8, k = idx & 255;
  Wt[idx] = (half_t)W[((size_t)((col >> 6) * HH + k)) * HDIM + (col & 63)];
}

// ---------------- GAT f_src/f_dst ----------------
__global__ void gat_fsd(const float* __restrict__ hgat, const float* __restrict__ a,
                        float* __restrict__ fsrc, float* __restrict__ fdst) {
  int b = blockIdx.x, hd = blockIdx.y, t = threadIdx.x;  // block 512
  const float* hp = hgat + ((size_t)(b * TT + t)) * HH + hd * HDIM;
  const float* ap = a + hd * 2 * HDIM;
  float fs = 0.f, fd = 0.f;
#pragma unroll 4
  for (int d = 0; d < HDIM; ++d) {
    float hv = hp[d];
    fs += hv * ap[d];
    fd += hv * ap[HDIM + d];
  }
  fsrc[(b * NHEADS + hd) * TT + t] = fs;
  fdst[(b * NHEADS + hd) * TT + t] = fd;
}

// ---------------- GAT flash attention ----------------
__global__ __launch_bounds__(256) void gat_attn(
    const float* __restrict__ hgat, const float* __restrict__ fsrc,
    const float* __restrict__ fdst, float* __restrict__ out) {
  __shared__ __align__(16) float Ht[128][64];
  __shared__ __align__(16) float fd[128];
  __shared__ __align__(16) float pq[4][128][8];
  const int tid = threadIdx.x, wave = tid >> 6, lane = tid & 63;
  const int hd = blockIdx.y, b = blockIdx.z;
  const int i0 = blockIdx.x * 32 + wave * 8;
  const float* fs = fsrc + (size_t)(b * NHEADS + hd) * TT;
  const float* fdp = fdst + (size_t)(b * NHEADS + hd) * TT;
  float m[8], l[8], acc[8], fi[8];
#pragma unroll
  for (int q = 0; q < 8; ++q) { m[q] = -1e30f; l[q] = 0.f; acc[q] = 0.f; fi[q] = fs[i0 + q]; }
  for (int jt = 0; jt < TT; jt += 128) {
#pragma unroll
    for (int u = 0; u < 8; ++u) {
      int idx = tid + u * 256;
      int jj = idx >> 4, dq = (idx & 15) * 4;
      *(float4*)&Ht[jj][dq] =
          *(const float4*)&hgat[((size_t)(b * TT + jt + jj)) * HH + hd * HDIM + dq];
    }
    if (tid < 128) fd[tid] = fdp[jt + tid];
    __syncthreads();
#pragma unroll
    for (int q = 0; q < 8; ++q) {
      float e0 = fi[q] + fd[lane];      e0 = (e0 > 0.f) ? e0 : 0.2f * e0;
      float e1 = fi[q] + fd[lane + 64]; e1 = (e1 > 0.f) ? e1 : 0.2f * e1;
      float mn = fmaxf(m[q], wmax(fmaxf(e0, e1)));
      float corr = __expf(m[q] - mn);
      float p0 = __expf(e0 - mn), p1 = __expf(e1 - mn);
      l[q] = l[q] * corr + wsum(p0 + p1);
      m[q] = mn;
      acc[q] *= corr;
      pq[wave][lane][q] = p0;
      pq[wave][lane + 64][q] = p1;
    }
#pragma unroll 4
    for (int jj = 0; jj < 128; ++jj) {
      float4 pa = *(const float4*)&pq[wave][jj][0];
      float4 pb = *(const float4*)&pq[wave][jj][4];
      float hv = Ht[jj][lane];
      acc[0] += pa.x * hv; acc[1] += pa.y * hv; acc[2] += pa.z * hv; acc[3] += pa.w * hv;
      acc[4] += pb.x * hv; acc[5] += pb.y * hv; acc[6] += pb.z * hv; acc[7] += pb.w * hv;
    }
    __syncthreads();
  }
#pragma unroll
  for (int q = 0; q < 8; ++q)
    out[((size_t)(b * TT + i0 + q)) * HH + hd * HDIM + lane] = acc[q] / l[q];
}

// ---------------- residual + LayerNorm (f16 output for MFMA GEMM) ---------
__global__ __launch_bounds__(256) void ln_res(
    const float* __restrict__ g, const float* __restrict__ gat,
    const float* __restrict__ gamma, const float* __restrict__ beta,
    half_t* __restrict__ y16) {
  int wave = threadIdx.x >> 6, lane = threadIdx.x & 63;
  size_t n = (size_t)blockIdx.x * 4 + wave;
  float4 v = ((const float4*)(g + n * HH))[lane];
  float4 w = ((const float4*)(gat + n * HH))[lane];
  v.x += w.x; v.y += w.y; v.z += w.z; v.w += w.w;
  float mu = wsum(v.x + v.y + v.z + v.w) * (1.f / 256.f);
  float dx = v.x - mu, dy = v.y - mu, dz = v.z - mu, dw = v.w - mu;
  float var = wsum(dx * dx + dy * dy + dz * dz + dw * dw) * (1.f / 256.f);
  float rstd = rsqrtf(var + 1e-5f);
  float4 gm = ((const float4*)gamma)[lane];
  float4 bt = ((const float4*)beta)[lane];
  half4_t o = {(half_t)(dx * rstd * gm.x + bt.x), (half_t)(dy * rstd * gm.y + bt.y),
               (half_t)(dz * rstd * gm.z + bt.z), (half_t)(dw * rstd * gm.w + bt.w)};
  ((half4_t*)(y16 + n * HH))[lane] = o;
}

// ---------------- MHA flash attention (f16 ctx output) --------------------
__global__ __launch_bounds__(256) void mha_attn(const float* __restrict__ qkv,
                                                half_t* __restrict__ ctx16) {
  __shared__ __align__(16) float KV[8320];        // K^T [64][130] | V [128][64]
  __shared__ __align__(16) float qq[4][64][8];
  __shared__ __align__(16) float pq[4][128][8];
  const int tid = threadIdx.x, wave = tid >> 6, lane = tid & 63;
  const int hd = blockIdx.y, b = blockIdx.z;
  const int i0 = blockIdx.x * 32 + wave * 8;
#pragma unroll
  for (int q = 0; q < 8; ++q)
    qq[wave][lane][q] = qkv[((size_t)(b * TT + i0 + q)) * H3 + hd * HDIM + lane];
  float m[8], l[8], acc[8];
#pragma unroll
  for (int q = 0; q < 8; ++q) { m[q] = -1e30f; l[q] = 0.f; acc[q] = 0.f; }
  for (int jt = 0; jt < TT; jt += 128) {
    // stage K^T: KV[dd*130 + j]
#pragma unroll
    for (int u = 0; u < 8; ++u) {
      int idx = tid + u * 256;
      int jj = idx >> 4, dq = (idx & 15) * 4;
      float4 kv = *(const float4*)&qkv[((size_t)(b * TT + jt + jj)) * H3 + HH + hd * HDIM + dq];
      KV[(dq + 0) * 130 + jj] = kv.x;
      KV[(dq + 1) * 130 + jj] = kv.y;
      KV[(dq + 2) * 130 + jj] = kv.z;
      KV[(dq + 3) * 130 + jj] = kv.w;
    }
    __syncthreads();
    float e0[8] = {}, e1[8] = {};
#pragma unroll 8
    for (int dd = 0; dd < 64; ++dd) {
      float4 qa = *(const float4*)&qq[wave][dd][0];
      float4 qb = *(const float4*)&qq[wave][dd][4];
      float k0 = KV[dd * 130 + lane], k1 = KV[dd * 130 + 64 + lane];
      e0[0] += qa.x * k0; e0[1] += qa.y * k0; e0[2] += qa.z * k0; e0[3] += qa.w * k0;
      e0[4] += qb.x * k0; e0[5] += qb.y * k0; e0[6] += qb.z * k0; e0[7] += qb.w * k0;
      e1[0] += qa.x * k1; e1[1] += qa.y * k1; e1[2] += qa.z * k1; e1[3] += qa.w * k1;
      e1[4] += qb.x * k1; e1[5] += qb.y * k1; e1[6] += qb.z * k1; e1[7] += qb.w * k1;
    }
    __syncthreads();  // done reading K^T
    // stage V over the same buffer: KV[j*64 + dd]
#pragma unroll
    for (int u = 0; u < 8; ++u) {
      int idx = tid + u * 256;
      int jj = idx >> 4, dq = (idx & 15) * 4;
      *(float4*)&KV[jj * 64 + dq] =
          *(const float4*)&qkv[((size_t)(b * TT + jt + jj)) * H3 + 2 * HH + hd * HDIM + dq];
    }
#pragma unroll
    for (int q = 0; q < 8; ++q) {
      float s0 = e0[q] * 0.125f, s1 = e1[q] * 0.125f;
      float mn = fmaxf(m[q], wmax(fmaxf(s0, s1)));
      float corr = __expf(m[q] - mn);
      float p0 = __expf(s0 - mn), p1 = __expf(s1 - mn);
      l[q] = l[q] * corr + wsum(p0 + p1);
      m[q] = mn;
      acc[q] *= corr;
      pq[wave][lane][q] = p0;
      pq[wave][lane + 64][q] = p1;
    }
    __syncthreads();  // V staged, pq written
#pragma unroll 4
    for (int jj = 0; jj < 128; ++jj) {
      float4 pa = *(const float4*)&pq[wave][jj][0];
      float4 pb = *(const float4*)&pq[wave][jj][4];
      float hv = KV[jj * 64 + lane];
      acc[0] += pa.x * hv; acc[1] += pa.y * hv; acc[2] += pa.z * hv; acc[3] += pa.w * hv;
      acc[4] += pb.x * hv; acc[5] += pb.y * hv; acc[6] += pb.z * hv; acc[7] += pb.w * hv;
    }
    __syncthreads();  // before next K^T overwrite
  }
#pragma unroll
  for (int q = 0; q < 8; ++q)
    ctx16[((size_t)(b * TT + i0 + q)) * HH + hd * HDIM + lane] = (half_t)(acc[q] / l[q]);
}

// ---------------- mean pool over T ----------------
__global__ void mean_pool(const float* __restrict__ x, float* __restrict__ out) {
  int b = blockIdx.x, j = threadIdx.x;
  const float* p = x + (size_t)b * TT * HH + j;
  float s = 0.f;
  for (int t = 0; t < TT; ++t) s += p[(size_t)t * HH];
  out[b * HH + j] = s * (1.f / 512.f);
}

// ---------------- FC layers ----------------
__global__ void fc1_k(const float* __restrict__ pooled, const float* __restrict__ w,
                      const float* __restrict__ bias, float* __restrict__ hid) {
  int b = blockIdx.x, o = threadIdx.x;  // 128 threads
  const float* pp = pooled + b * HH;
  const float* wp = w + o * HH;
  float s = 0.f;
#pragma unroll 4
  for (int k = 0; k < HH; ++k) s += pp[k] * wp[k];
  hid[b * 128 + o] = fmaxf(s + bias[o], 0.f);
}

__global__ void fc2_k(const float* __restrict__ hid, const float* __restrict__ w,
                      const float* __restrict__ bias, float* __restrict__ out) {
  int t = threadIdx.x;  // 256 = 32 m x 8 c
  int mm = t >> 3, c = t & 7;
  const float* hp = hid + mm * 128;
  const float* wp = w + c * 128;
  float s = 0.f;
#pragma unroll 4
  for (int k = 0; k < 128; ++k) s += hp[k] * wp[k];
  out[mm * 8 + c] = s + bias[c];
}

extern "C" void kernel_launch(void* const* d_in, const int* in_sizes, int n_in,
                              void* d_out, int out_size, void* d_ws, size_t ws_size,
                              hipStream_t stream) {
  (void)in_sizes; (void)n_in; (void)out_size; (void)ws_size;
  const float* x    = (const float*)d_in[0];
  const float* Wih0 = (const float*)d_in[1];
  const float* Whh0 = (const float*)d_in[2];
  const float* bih0 = (const float*)d_in[3];
  const float* bhh0 = (const float*)d_in[4];
  const float* Wih1 = (const float*)d_in[5];
  const float* Whh1 = (const float*)d_in[6];
  const float* bih1 = (const float*)d_in[7];
  const float* bhh1 = (const float*)d_in[8];
  const float* gatW = (const float*)d_in[9];
  const float* gatA = (const float*)d_in[10];
  const float* lng  = (const float*)d_in[11];
  const float* lnb  = (const float*)d_in[12];
  const float* inw  = (const float*)d_in[13];
  const float* inb  = (const float*)d_in[14];
  const float* outw = (const float*)d_in[15];
  const float* outb = (const float*)d_in[16];
  const float* f1w  = (const float*)d_in[17];
  const float* f1b  = (const float*)d_in[18];
  const float* f2w  = (const float*)d_in[19];
  const float* f2b  = (const float*)d_in[20];
  float* out = (float*)d_out;
  float* ws = (float*)d_ws;

  // fp32 regions:
  float* XPA   = ws;                  // 16384*768: xp0 -> xp1 -> qkv
  float* G0    = ws + 12582912;       // gat_out (gru0 fp32 h never stored)
  float* G1    = G0 + 4194304;        // gru1-out (fp32, for ln_res)
  float* Yb    = G1 + 4194304;        // [f16 G0_16 | f16 G1_16] -> attn_out fp32
  float* HGAT  = Yb + 4194304;        // gat feats fp32 -> [f16 CTX16 | f16 Y16]
  float* GATWTf= HGAT + 4194304;
  float* FSRC  = GATWTf + 65536;
  float* FDST  = FSRC + 65536;
  float* POOL  = FDST + 65536;
  float* HIDb  = POOL + 8192;
  float* W16b  = HIDb + 4096;         // f16 weight pool (~1.1 MB)

  // f16 aliases (lifetimes verified against launch order):
  half_t* X16     = (half_t*)G1;                   // dead before gru1 writes G1
  half_t* G0_16   = (half_t*)Yb;                   // dead before attn_out write
  half_t* G1_16   = (half_t*)(Yb + 2097152);
  half_t* CTX16   = (half_t*)HGAT;                 // written after gat phase done
  half_t* Y16     = (half_t*)(HGAT + 2097152);
  half_t* GATWT16 = (half_t*)GATWTf;
  half_t* W16ih0  = (half_t*)W16b;
  half_t* W16ih1  = (half_t*)(W16b + 49152);
  half_t* W16in   = (half_t*)(W16b + 49152 + 98304);
  half_t* W16out  = (half_t*)(W16b + 49152 + 98304 + 98304);

  // 0. casts (weights once; x once)
  castk<<<2048, 256, 0, stream>>>(x, X16, 2097152);
  castk<<<96, 256, 0, stream>>>(Wih0, W16ih0, 98304);
  castk<<<192, 256, 0, stream>>>(Wih1, W16ih1, 196608);
  castk<<<192, 256, 0, stream>>>(inw, W16in, 196608);
  castk<<<64, 256, 0, stream>>>(outw, W16out, 65536);
  gat_wt<<<256, 256, 0, stream>>>(gatW, GATWT16);
  // 1. xp0 = x @ W_ih0^T + b_ih0   (MFMA f16)
  gemm_f16<<<dim3(12, 128), 256, 0, stream>>>(X16, W16ih0, bih0, XPA, 16384, 768, 128);
  // 2. GRU layer 0 (fp32 h not needed -> nullptr)
  gru_layer<<<32, 768, 0, stream>>>(XPA, Whh0, bhh0, nullptr, G0_16);
  // 3. xp1 = g0 @ W_ih1^T + b_ih1
  gemm_f16<<<dim3(12, 128), 256, 0, stream>>>(G0_16, W16ih1, bih1, XPA, 16384, 768, 256);
  // 4. GRU layer 1
  gru_layer<<<32, 768, 0, stream>>>(XPA, Whh1, bhh1, G1, G1_16);
  // 5. GAT per-head features + attention
  gemm_f16<<<dim3(4, 128), 256, 0, stream>>>(G1_16, GATWT16, nullptr, HGAT, 16384, 256, 256);
  gat_fsd<<<dim3(32, 4), 512, 0, stream>>>(HGAT, gatA, FSRC, FDST);
  gat_attn<<<dim3(16, 4, 32), 256, 0, stream>>>(HGAT, FSRC, FDST, G0);
  // 6. y = LN(g + gat_out) -> f16
  ln_res<<<4096, 256, 0, stream>>>(G1, G0, lng, lnb, Y16);
  // 7. MHA
  gemm_f16<<<dim3(12, 128), 256, 0, stream>>>(Y16, W16in, inb, XPA, 16384, 768, 256);
  mha_attn<<<dim3(16, 4, 32), 256, 0, stream>>>(XPA, CTX16);
  gemm_f16<<<dim3(4, 128), 256, 0, stream>>>(CTX16, W16out, outb, Yb, 16384, 256, 256);
  // 8. pool + FC head
  mean_pool<<<32, 256, 0, stream>>>(Yb, POOL);
  fc1_k<<<32, 128, 0, stream>>>(POOL, f1w, f1b, HIDb);
  fc2_k<<<1, 256, 0, stream>>>(HIDb, f2w, f2b, out);
}